// Round 5
// baseline (293.503 us; speedup 1.0000x reference)
//
#include <hip/hip_runtime.h>

#define CDIM 64

typedef __attribute__((ext_vector_type(8))) short bf16x8;
typedef __attribute__((ext_vector_type(4))) float f32x4;

// round-to-nearest-even fp32 -> bf16 (as short)
__device__ __forceinline__ short bf16r(float f) {
    unsigned a = __float_as_uint(f);
    a = (a + 0x7fffu + ((a >> 16) & 1u)) >> 16;
    return (short)a;
}
// pack two fp32 as bf16 pair: first -> bits[15:0], second -> bits[31:16]
__device__ __forceinline__ unsigned bfpack(float lo, float hi) {
    unsigned a = __float_as_uint(lo);
    a = (a + 0x7fffu + ((a >> 16) & 1u)) >> 16;
    unsigned b = __float_as_uint(hi);
    b = (b + 0x7fffu + ((b >> 16) & 1u)) & 0xffff0000u;
    return a | b;
}

// --- pack x (fp32) -> bf16 pairs (u32 per 2 channels) ---
__global__ __launch_bounds__(256) void k_pack(const float* __restrict__ x,
                                              unsigned* __restrict__ xb32, size_t n2) {
    size_t t = (size_t)blockIdx.x * 256 + threadIdx.x;
    size_t stride = (size_t)gridDim.x * 256;
    for (size_t i = t; i < n2; i += stride) {
        float2 v = ((const float2*)x)[i];
        xb32[i] = bfpack(v.x, v.y);
    }
}

// ===== CSR build: zero per-edge global atomics (R3) =====
#define NPB_SHIFT 9                     // 512 nodes per bucket
#define BKN (1 << NPB_SHIFT)
#define BPAD 10240                      // record slots per bucket (mean 8163, sd 90)
#define PART_CH 2048                    // edges per k_part block

// block 0: init padded bucket cursors; blocks 1,2: pre-transpose weights to
// bf16 n-major (wtg[l][m][n][k]) so k_fused reads B-fragments straight from
// global (48KB, L2-broadcast) -- no 27KB wt LDS per block.
__global__ __launch_bounds__(256) void k_prep(int* __restrict__ bkt_cursor, int n_buckets,
                                              const float* __restrict__ w1,
                                              const float* __restrict__ root1,
                                              const float* __restrict__ w2,
                                              const float* __restrict__ root2,
                                              short* __restrict__ wtg) {
    int tid = threadIdx.x;
    if (blockIdx.x == 0) {
        if (tid < n_buckets) bkt_cursor[tid] = tid * BPAD;
        return;
    }
    int l = blockIdx.x - 1;
    const float* s0 = l ? w2 : w1;
    const float* srcs[3] = {s0, s0 + 4096, l ? root2 : root1};
    short* o = wtg + (size_t)l * 3 * 4096;
    for (int i = tid; i < 12288; i += 256) {
        int m = i >> 12, r = i & 4095, k = r >> 6, n = r & 63;  // w row-major [k][n]
        o[(m << 12) + (n << 6) + k] = bf16r(srcs[m][r]);
    }
}

// phase A: bin edges -> bucket-major padded records (d<<32 | s<<15 | u15).
__global__ __launch_bounds__(256) void k_part(const int* __restrict__ src,
                                              const int* __restrict__ dst,
                                              const float* __restrict__ u,
                                              int* __restrict__ bkt_cursor,
                                              unsigned long long* __restrict__ rec,
                                              int n_edges, int n_buckets) {
    __shared__ int cnt_s[256];
    __shared__ int off_s[256];
    int tid = threadIdx.x;
    cnt_s[tid] = 0;
    __syncthreads();
    int e0 = blockIdx.x * PART_CH + tid * 8;
    int d[8], s[8];
    float uu[8];
    if (e0 + 8 <= n_edges) {
        int4 d0 = *(const int4*)(dst + e0), d1 = *(const int4*)(dst + e0 + 4);
        int4 s0 = *(const int4*)(src + e0), s1 = *(const int4*)(src + e0 + 4);
        float4 u0 = *(const float4*)(u + e0), u1 = *(const float4*)(u + e0 + 4);
        d[0]=d0.x; d[1]=d0.y; d[2]=d0.z; d[3]=d0.w; d[4]=d1.x; d[5]=d1.y; d[6]=d1.z; d[7]=d1.w;
        s[0]=s0.x; s[1]=s0.y; s[2]=s0.z; s[3]=s0.w; s[4]=s1.x; s[5]=s1.y; s[6]=s1.z; s[7]=s1.w;
        uu[0]=u0.x; uu[1]=u0.y; uu[2]=u0.z; uu[3]=u0.w; uu[4]=u1.x; uu[5]=u1.y; uu[6]=u1.z; uu[7]=u1.w;
    } else {
#pragma unroll
        for (int i = 0; i < 8; ++i) {
            int e = e0 + i;
            bool ok = e < n_edges;
            d[i] = ok ? dst[e] : -1;
            s[i] = ok ? src[e] : 0;
            uu[i] = ok ? u[e] : 0.f;
        }
    }
#pragma unroll
    for (int i = 0; i < 8; ++i)
        if (d[i] >= 0) atomicAdd(&cnt_s[d[i] >> NPB_SHIFT], 1);
    __syncthreads();
    if (tid < n_buckets) {
        int c = cnt_s[tid];
        off_s[tid] = c ? atomicAdd(&bkt_cursor[tid], c) : 0;
    }
    __syncthreads();
#pragma unroll
    for (int i = 0; i < 8; ++i) {
        if (d[i] >= 0) {
            int b = d[i] >> NPB_SHIFT;
            int p = atomicAdd(&off_s[b], 1);
            unsigned uq = (unsigned)(uu[i] * 32767.0f + 0.5f);
            rec[p] = ((unsigned long long)(unsigned)d[i] << 32)
                   | (unsigned long long)(((unsigned)s[i] << 15) | uq);
        }
    }
}

// tiny scan over bucket sizes -> dense em32 bases
__global__ __launch_bounds__(256) void k_bscan(const int* __restrict__ bkt_cursor,
                                               int* __restrict__ ebase,
                                               int* __restrict__ row_start,
                                               int n_buckets, int n_nodes) {
    __shared__ int sm[256];
    int tid = threadIdx.x;
    int v = (tid < n_buckets) ? (bkt_cursor[tid] - tid * BPAD) : 0;
    sm[tid] = v;
    __syncthreads();
    for (int off = 1; off < 256; off <<= 1) {
        int t = (tid >= off) ? sm[tid - off] : 0;
        __syncthreads();
        sm[tid] += t;
        __syncthreads();
    }
    if (tid < n_buckets) ebase[tid] = sm[tid] - v;   // exclusive
    if (tid == 255) row_start[n_nodes] = sm[255];    // grand total (= n_edges)
}

// phase B: one 1024-thread block per bucket; LDS hist->scan->scatter.
__global__ __launch_bounds__(1024) void k_scat2(const unsigned long long* __restrict__ rec,
                                                const int* __restrict__ bkt_cursor,
                                                const int* __restrict__ ebase,
                                                int* __restrict__ row_start,
                                                unsigned* __restrict__ em32,
                                                int n_nodes) {
    __shared__ int cnt_s[BKN];   // per-node count, then running cursor
    __shared__ int sc_s[BKN];    // inclusive scan
    int tid = threadIdx.x;
    int b = blockIdx.x;
    int lo = b << NPB_SHIFT;
    int nrec = bkt_cursor[b] - b * BPAD;
    const unsigned long long* r0 = rec + (size_t)b * BPAD;
    int eb = ebase[b];

    if (tid < BKN) cnt_s[tid] = 0;
    __syncthreads();
    for (int i = tid; i < nrec; i += 1024) {
        int d = (int)(r0[i] >> 32) - lo;
        atomicAdd(&cnt_s[d], 1);
    }
    __syncthreads();
    if (tid < BKN) sc_s[tid] = cnt_s[tid];
    __syncthreads();
    for (int off = 1; off < BKN; off <<= 1) {
        int t = 0;
        if (tid < BKN && tid >= off) t = sc_s[tid - off];
        __syncthreads();
        if (tid < BKN) sc_s[tid] += t;
        __syncthreads();
    }
    if (tid < BKN) {
        int excl = sc_s[tid] - cnt_s[tid];
        int node = lo + tid;
        if (node < n_nodes) row_start[node] = eb + excl;
        cnt_s[tid] = excl;   // becomes cursor
    }
    __syncthreads();
    for (int i = tid; i < nrec; i += 1024) {
        unsigned long long r = r0[i];
        int d = (int)(r >> 32) - lo;
        int p = atomicAdd(&cnt_s[d], 1);
        em32[eb + p] = (unsigned)r;
    }
}

// ===== R4: fused aggregate+GEMM layer kernel =====
// R4 counters: k_aggx 46us x2 with WRITE=50MB -- 'g' is a pure fp32
// intermediate that k_gemm reads back and converts to bf16 anyway; gemm's xr
// fp32 read likewise duplicates the existing bf16 xb buffer bit-for-bit.
// Fuse: each 4-wave block aggregates its own 64 nodes into a 17KB bf16 LDS
// tile (wave w aggregates nodes w*16..w*16+15 -- exactly its MFMA A-tile),
// then runs the MFMA epilogue from LDS. Eliminates per layer: g write (51MB)
// + g read (51MB) + xr read (25.6MB); layer-1 output is bf16-only (xbB).
// B-fragments come from pre-transposed bf16 weights in global (L2-broadcast).
__global__ __launch_bounds__(256, 4) void k_fused(
        const unsigned* __restrict__ xb_in,   // bf16 rows [n][32] u32 pairs
        const unsigned* __restrict__ em32,
        const int* __restrict__ row_start,
        const short* __restrict__ wb,         // [3][64][64] bf16 (n-major, k-contig)
        const float* __restrict__ bias,
        float* __restrict__ out,              // fp32 out (layer 2) or null
        unsigned short* __restrict__ xb_out,  // bf16 out (layer 1) or null
        int n_nodes) {
    __shared__ __align__(16) unsigned gl[64][68];  // [node][word]: w0..31=g0, 32..63=g1; pad->68 (2-way bank max)
    int wave = threadIdx.x >> 6;
    int lane = threadIdx.x & 63;
    int half = lane >> 5;        // edge parity handled by this half-wave
    int hl = lane & 31;          // channel-pair index
    int nodew = blockIdx.x * 64 + wave * 16;
    const float inv15 = 1.0f / 32767.0f;

    // --- aggregation: wave w handles its own 16 A-tile rows ---
    for (int t = 0; t < 16; ++t) {
        int n = nodew + t;
        if (n >= n_nodes) break;
        int start = row_start[n];
        int end = row_start[n + 1];
        float g0a = 0.f, g0b = 0.f, g1a = 0.f, g1b = 0.f;
        int j = start;
        for (; j + 8 <= end; j += 8) {
            unsigned e[4], v[4];
#pragma unroll
            for (int i = 0; i < 4; ++i) e[i] = em32[j + 2 * i + half];
#pragma unroll
            for (int i = 0; i < 4; ++i) v[i] = xb_in[(size_t)(e[i] >> 15) * 32 + hl];
#pragma unroll
            for (int i = 0; i < 4; ++i) {
                float uu = (float)(e[i] & 0x7fffu) * inv15;
                float c0 = __uint_as_float(v[i] << 16);
                float c1 = __uint_as_float(v[i] & 0xffff0000u);
                float wa = 1.0f - uu;
                g0a += wa * c0; g0b += wa * c1;
                g1a += uu * c0; g1b += uu * c1;
            }
        }
        if (j < end) {   // masked final group (1..7 edges)
            unsigned e[4], v[4];
            float m[4];
#pragma unroll
            for (int i = 0; i < 4; ++i) {
                int idx = j + 2 * i + half;
                bool ok = idx < end;
                e[i] = em32[ok ? idx : (end - 1)];
                m[i] = ok ? 1.0f : 0.0f;
            }
#pragma unroll
            for (int i = 0; i < 4; ++i) v[i] = xb_in[(size_t)(e[i] >> 15) * 32 + hl];
#pragma unroll
            for (int i = 0; i < 4; ++i) {
                float uu = (float)(e[i] & 0x7fffu) * inv15;
                float c0 = __uint_as_float(v[i] << 16);
                float c1 = __uint_as_float(v[i] & 0xffff0000u);
                float wa = (1.0f - uu) * m[i], wb2 = uu * m[i];
                g0a += wa * c0; g0b += wa * c1;
                g1a += wb2 * c0; g1b += wb2 * c1;
            }
        }
        g0a += __shfl_xor(g0a, 32);
        g0b += __shfl_xor(g0b, 32);
        g1a += __shfl_xor(g1a, 32);
        g1b += __shfl_xor(g1b, 32);
        float s = 1.0f / fmaxf((float)(end - start), 1.0f);
        if (half == 0) {   // bfpack == old (store fp32; bf16r on load) bit-for-bit
            gl[wave * 16 + t][hl] = bfpack(g0a * s, g0b * s);
            gl[wave * 16 + t][32 + hl] = bfpack(g1a * s, g1b * s);
        }
    }
    __syncthreads();

    // --- MFMA epilogue (m92-verified layout) ---
    int quad = lane >> 4;
    int m16 = lane & 15;
    int arow = nodew + m16;
    const short* gp = (const short*)&gl[wave * 16 + m16][0];
    const unsigned* xp = xb_in + (size_t)arow * 32;
    bf16x8 zf = {0, 0, 0, 0, 0, 0, 0, 0};
    bf16x8 aG0[2], aG1[2], aX[2];
#pragma unroll
    for (int kf = 0; kf < 2; ++kf) {
        aG0[kf] = *(const bf16x8*)(gp + kf * 32 + quad * 8);
        aG1[kf] = *(const bf16x8*)(gp + 64 + kf * 32 + quad * 8);
        aX[kf] = (arow < n_nodes) ? *(const bf16x8*)(xp + kf * 16 + quad * 4) : zf;
    }
#pragma unroll
    for (int nt = 0; nt < 4; ++nt) {
        f32x4 acc = {0.f, 0.f, 0.f, 0.f};
#pragma unroll
        for (int kf = 0; kf < 2; ++kf) {
            int col = nt * 16 + m16;
            bf16x8 b0 = *(const bf16x8*)(wb + (col << 6) + kf * 32 + quad * 8);
            bf16x8 b1 = *(const bf16x8*)(wb + ((64 + col) << 6) + kf * 32 + quad * 8);
            bf16x8 bR = *(const bf16x8*)(wb + ((128 + col) << 6) + kf * 32 + quad * 8);
            acc = __builtin_amdgcn_mfma_f32_16x16x32_bf16(aG0[kf], b0, acc, 0, 0, 0);
            acc = __builtin_amdgcn_mfma_f32_16x16x32_bf16(aG1[kf], b1, acc, 0, 0, 0);
            acc = __builtin_amdgcn_mfma_f32_16x16x32_bf16(aX[kf], bR, acc, 0, 0, 0);
        }
        float bcol = bias[nt * 16 + m16];
#pragma unroll
        for (int r = 0; r < 4; ++r) {
            int node = nodew + quad * 4 + r;
            if (node < n_nodes) {
                size_t off = (size_t)node * CDIM + nt * 16 + m16;
                float o = acc[r] + bcol;
                if (out) out[off] = o;
                if (xb_out) xb_out[off] = (unsigned short)bf16r(o);
            }
        }
    }
}

extern "C" void kernel_launch(void* const* d_in, const int* in_sizes, int n_in,
                              void* d_out, int out_size, void* d_ws, size_t ws_size,
                              hipStream_t stream) {
    const float* x = (const float*)d_in[0];
    const int* edge_index = (const int*)d_in[1];
    const float* edge_attr = (const float*)d_in[2];
    const float* w1 = (const float*)d_in[3];
    const float* root1 = (const float*)d_in[4];
    const float* b1 = (const float*)d_in[5];
    const float* w2 = (const float*)d_in[6];
    const float* root2 = (const float*)d_in[7];
    const float* b2 = (const float*)d_in[8];

    int n_nodes = in_sizes[0] / CDIM;
    int n_edges = in_sizes[2];
    const int* src = edge_index;
    const int* dst = edge_index + n_edges;

    size_t F = (size_t)n_nodes * CDIM;
    unsigned* xbA = (unsigned*)d_ws;              // F/2 u32: bf16(x)
    unsigned* xbB = xbA + F / 2;                  // F/2 u32: bf16(layer-1 out)
    unsigned* em32 = xbB + F / 2;                 // E u32 (src<<15 | u15)
    int* row_start = (int*)(em32 + n_edges);      // n+1
    int n_buckets = (n_nodes + BKN - 1) >> NPB_SHIFT;   // 196
    int* ebase = row_start + n_nodes + 1;         // n_buckets
    int* bkt_cursor = ebase + n_buckets;          // n_buckets
    uintptr_t p = (uintptr_t)(bkt_cursor + n_buckets);
    p = (p + 15) & ~(uintptr_t)15;
    short* wtg = (short*)p;                       // [2][3][64][64] bf16
    p += (size_t)2 * 3 * 4096 * sizeof(short);
    p = (p + 15) & ~(uintptr_t)15;
    unsigned long long* rec = (unsigned long long*)p;  // n_buckets*BPAD u64
    float* out = (float*)d_out;

    int gB = (n_nodes + 63) / 64;                 // 64 nodes per fused block
    int gP = (n_edges + PART_CH - 1) / PART_CH;   // 782

    // ---- CSR build + packs/preps ----
    k_pack<<<2048, 256, 0, stream>>>(x, xbA, F / 2);
    k_prep<<<3, 256, 0, stream>>>(bkt_cursor, n_buckets, w1, root1, w2, root2, wtg);
    k_part<<<gP, 256, 0, stream>>>(src, dst, edge_attr, bkt_cursor, rec, n_edges, n_buckets);
    k_bscan<<<1, 256, 0, stream>>>(bkt_cursor, ebase, row_start, n_buckets, n_nodes);
    k_scat2<<<n_buckets, 1024, 0, stream>>>(rec, bkt_cursor, ebase, row_start, em32, n_nodes);

    // ---- layer 1 (bf16 out only) ----
    k_fused<<<gB, 256, 0, stream>>>(xbA, em32, row_start, wtg, b1,
                                    nullptr, (unsigned short*)xbB, n_nodes);
    // ---- layer 2 (fp32 out) ----
    k_fused<<<gB, 256, 0, stream>>>(xbB, em32, row_start, wtg + 3 * 4096, b2,
                                    out, nullptr, n_nodes);
}

// Round 6
// 268.289 us; speedup vs baseline: 1.0940x; 1.0940x over previous
//
#include <hip/hip_runtime.h>

#define CDIM 64

typedef __attribute__((ext_vector_type(8))) short bf16x8;
typedef __attribute__((ext_vector_type(4))) float f32x4;

// round-to-nearest-even fp32 -> bf16 (as short)
__device__ __forceinline__ short bf16r(float f) {
    unsigned a = __float_as_uint(f);
    a = (a + 0x7fffu + ((a >> 16) & 1u)) >> 16;
    return (short)a;
}
// pack two fp32 as bf16 pair: first -> bits[15:0], second -> bits[31:16]
__device__ __forceinline__ unsigned bfpack(float lo, float hi) {
    unsigned a = __float_as_uint(lo);
    a = (a + 0x7fffu + ((a >> 16) & 1u)) >> 16;
    unsigned b = __float_as_uint(hi);
    b = (b + 0x7fffu + ((b >> 16) & 1u)) & 0xffff0000u;
    return a | b;
}

// --- pack x (fp32) -> bf16 pairs (u32 per 2 channels) ---
__global__ __launch_bounds__(256) void k_pack(const float* __restrict__ x,
                                              unsigned* __restrict__ xb32, size_t n2) {
    size_t t = (size_t)blockIdx.x * 256 + threadIdx.x;
    size_t stride = (size_t)gridDim.x * 256;
    for (size_t i = t; i < n2; i += stride) {
        float2 v = ((const float2*)x)[i];
        xb32[i] = bfpack(v.x, v.y);
    }
}

// ===== CSR build: zero per-edge global atomics (R3) =====
#define NPB_SHIFT 9                     // 512 nodes per bucket
#define BKN (1 << NPB_SHIFT)
#define BPAD 10240                      // record slots per bucket (mean 8163, sd 90)
#define PART_CH 2048                    // edges per k_part block

// block 0: init padded bucket cursors; blocks 1,2: pre-transpose weights to
// bf16 n-major (wtg[l][m][n][k]) so k_fused reads B-fragments straight from
// global (48KB, L2-broadcast).
__global__ __launch_bounds__(256) void k_prep(int* __restrict__ bkt_cursor, int n_buckets,
                                              const float* __restrict__ w1,
                                              const float* __restrict__ root1,
                                              const float* __restrict__ w2,
                                              const float* __restrict__ root2,
                                              short* __restrict__ wtg) {
    int tid = threadIdx.x;
    if (blockIdx.x == 0) {
        if (tid < n_buckets) bkt_cursor[tid] = tid * BPAD;
        return;
    }
    int l = blockIdx.x - 1;
    const float* s0 = l ? w2 : w1;
    const float* srcs[3] = {s0, s0 + 4096, l ? root2 : root1};
    short* o = wtg + (size_t)l * 3 * 4096;
    for (int i = tid; i < 12288; i += 256) {
        int m = i >> 12, r = i & 4095, k = r >> 6, n = r & 63;  // w row-major [k][n]
        o[(m << 12) + (n << 6) + k] = bf16r(srcs[m][r]);
    }
}

// phase A: bin edges -> bucket-major padded records (d<<32 | s<<15 | u15).
__global__ __launch_bounds__(256) void k_part(const int* __restrict__ src,
                                              const int* __restrict__ dst,
                                              const float* __restrict__ u,
                                              int* __restrict__ bkt_cursor,
                                              unsigned long long* __restrict__ rec,
                                              int n_edges, int n_buckets) {
    __shared__ int cnt_s[256];
    __shared__ int off_s[256];
    int tid = threadIdx.x;
    cnt_s[tid] = 0;
    __syncthreads();
    int e0 = blockIdx.x * PART_CH + tid * 8;
    int d[8], s[8];
    float uu[8];
    if (e0 + 8 <= n_edges) {
        int4 d0 = *(const int4*)(dst + e0), d1 = *(const int4*)(dst + e0 + 4);
        int4 s0 = *(const int4*)(src + e0), s1 = *(const int4*)(src + e0 + 4);
        float4 u0 = *(const float4*)(u + e0), u1 = *(const float4*)(u + e0 + 4);
        d[0]=d0.x; d[1]=d0.y; d[2]=d0.z; d[3]=d0.w; d[4]=d1.x; d[5]=d1.y; d[6]=d1.z; d[7]=d1.w;
        s[0]=s0.x; s[1]=s0.y; s[2]=s0.z; s[3]=s0.w; s[4]=s1.x; s[5]=s1.y; s[6]=s1.z; s[7]=s1.w;
        uu[0]=u0.x; uu[1]=u0.y; uu[2]=u0.z; uu[3]=u0.w; uu[4]=u1.x; uu[5]=u1.y; uu[6]=u1.z; uu[7]=u1.w;
    } else {
#pragma unroll
        for (int i = 0; i < 8; ++i) {
            int e = e0 + i;
            bool ok = e < n_edges;
            d[i] = ok ? dst[e] : -1;
            s[i] = ok ? src[e] : 0;
            uu[i] = ok ? u[e] : 0.f;
        }
    }
#pragma unroll
    for (int i = 0; i < 8; ++i)
        if (d[i] >= 0) atomicAdd(&cnt_s[d[i] >> NPB_SHIFT], 1);
    __syncthreads();
    if (tid < n_buckets) {
        int c = cnt_s[tid];
        off_s[tid] = c ? atomicAdd(&bkt_cursor[tid], c) : 0;
    }
    __syncthreads();
#pragma unroll
    for (int i = 0; i < 8; ++i) {
        if (d[i] >= 0) {
            int b = d[i] >> NPB_SHIFT;
            int p = atomicAdd(&off_s[b], 1);
            unsigned uq = (unsigned)(uu[i] * 32767.0f + 0.5f);
            rec[p] = ((unsigned long long)(unsigned)d[i] << 32)
                   | (unsigned long long)(((unsigned)s[i] << 15) | uq);
        }
    }
}

// tiny scan over bucket sizes -> dense em32 bases
__global__ __launch_bounds__(256) void k_bscan(const int* __restrict__ bkt_cursor,
                                               int* __restrict__ ebase,
                                               int* __restrict__ row_start,
                                               int n_buckets, int n_nodes) {
    __shared__ int sm[256];
    int tid = threadIdx.x;
    int v = (tid < n_buckets) ? (bkt_cursor[tid] - tid * BPAD) : 0;
    sm[tid] = v;
    __syncthreads();
    for (int off = 1; off < 256; off <<= 1) {
        int t = (tid >= off) ? sm[tid - off] : 0;
        __syncthreads();
        sm[tid] += t;
        __syncthreads();
    }
    if (tid < n_buckets) ebase[tid] = sm[tid] - v;   // exclusive
    if (tid == 255) row_start[n_nodes] = sm[255];    // grand total (= n_edges)
}

// phase B: one 1024-thread block per bucket; LDS hist->scan->scatter.
__global__ __launch_bounds__(1024) void k_scat2(const unsigned long long* __restrict__ rec,
                                                const int* __restrict__ bkt_cursor,
                                                const int* __restrict__ ebase,
                                                int* __restrict__ row_start,
                                                unsigned* __restrict__ em32,
                                                int n_nodes) {
    __shared__ int cnt_s[BKN];   // per-node count, then running cursor
    __shared__ int sc_s[BKN];    // inclusive scan
    int tid = threadIdx.x;
    int b = blockIdx.x;
    int lo = b << NPB_SHIFT;
    int nrec = bkt_cursor[b] - b * BPAD;
    const unsigned long long* r0 = rec + (size_t)b * BPAD;
    int eb = ebase[b];

    if (tid < BKN) cnt_s[tid] = 0;
    __syncthreads();
    for (int i = tid; i < nrec; i += 1024) {
        int d = (int)(r0[i] >> 32) - lo;
        atomicAdd(&cnt_s[d], 1);
    }
    __syncthreads();
    if (tid < BKN) sc_s[tid] = cnt_s[tid];
    __syncthreads();
    for (int off = 1; off < BKN; off <<= 1) {
        int t = 0;
        if (tid < BKN && tid >= off) t = sc_s[tid - off];
        __syncthreads();
        if (tid < BKN) sc_s[tid] += t;
        __syncthreads();
    }
    if (tid < BKN) {
        int excl = sc_s[tid] - cnt_s[tid];
        int node = lo + tid;
        if (node < n_nodes) row_start[node] = eb + excl;
        cnt_s[tid] = excl;   // becomes cursor
    }
    __syncthreads();
    for (int i = tid; i < nrec; i += 1024) {
        unsigned long long r = r0[i];
        int d = (int)(r >> 32) - lo;
        int p = atomicAdd(&cnt_s[d], 1);
        em32[eb + p] = (unsigned)r;
    }
}

// ===== R5: fused layer kernel, quarter-wave aggregation =====
// R5 counters: 16-nodes-serial-per-wave fused kernel ran at 1.55 TB/s vs
// aggx's 2.96 -- wave count dropped 100K->6.2K with unchanged per-wave MLP,
// plus a block barrier. Fix: each QUARTER-wave (16 lanes x uint2 = all 64
// channels) aggregates one node alone: 4 nodes in flight/wave (16 gathers
// outstanding vs 8), serial chain 16->4 nodes, no shfl reduction, and NO
// __syncthreads (each wave's MFMA reads only LDS rows its own lanes wrote;
// program order + lgkmcnt orders ds_write->ds_read within a wave).
__global__ __launch_bounds__(256) void k_fused(
        const unsigned* __restrict__ xb_in,   // bf16 rows [n][32] u32 pairs
        const unsigned* __restrict__ em32,
        const int* __restrict__ row_start,
        const short* __restrict__ wb,         // [3][64][64] bf16 (n-major, k-contig)
        const float* __restrict__ bias,
        float* __restrict__ out,              // fp32 out (layer 2) or null
        unsigned short* __restrict__ xb_out,  // bf16 out (layer 1) or null
        int n_nodes) {
    __shared__ __align__(16) unsigned gl[64][68];  // [node][word]: 0..31=g0, 32..63=g1; pad->68
    int wave = threadIdx.x >> 6;
    int lane = threadIdx.x & 63;
    int q = lane >> 4;           // quarter = which node of the group of 4
    int ql = lane & 15;          // word-pair index: words 2ql,2ql+1 (channels 4ql..4ql+3)
    int nodew = blockIdx.x * 64 + wave * 16;
    const float inv15 = 1.0f / 32767.0f;

    // --- aggregation: quarter q handles nodes nodew + q*4 + t, t=0..3 ---
    for (int t = 0; t < 4; ++t) {
        int n = nodew + q * 4 + t;
        bool nok = n < n_nodes;
        int start = nok ? row_start[n] : 0;
        int end = nok ? row_start[n + 1] : 0;
        float a0 = 0.f, a1 = 0.f, a2 = 0.f, a3 = 0.f;   // g0, channels 4ql..4ql+3
        float b0 = 0.f, b1 = 0.f, b2 = 0.f, b3 = 0.f;   // g1
        int j = start;
        for (; j + 4 <= end; j += 4) {
            unsigned e[4];
            uint2 v[4];
#pragma unroll
            for (int i = 0; i < 4; ++i) e[i] = em32[j + i];
#pragma unroll
            for (int i = 0; i < 4; ++i)
                v[i] = *(const uint2*)(xb_in + (size_t)(e[i] >> 15) * 32 + 2 * ql);
#pragma unroll
            for (int i = 0; i < 4; ++i) {
                float uu = (float)(e[i] & 0x7fffu) * inv15;
                float wa = 1.0f - uu;
                float c0 = __uint_as_float(v[i].x << 16);
                float c1 = __uint_as_float(v[i].x & 0xffff0000u);
                float c2 = __uint_as_float(v[i].y << 16);
                float c3 = __uint_as_float(v[i].y & 0xffff0000u);
                a0 += wa * c0; a1 += wa * c1; a2 += wa * c2; a3 += wa * c3;
                b0 += uu * c0; b1 += uu * c1; b2 += uu * c2; b3 += uu * c3;
            }
        }
        if (j < end) {   // masked tail (1..3 edges)
            unsigned e[4];
            uint2 v[4];
            float m[4];
#pragma unroll
            for (int i = 0; i < 4; ++i) {
                int idx = j + i;
                bool ok = idx < end;
                e[i] = em32[ok ? idx : (end - 1)];
                m[i] = ok ? 1.0f : 0.0f;
            }
#pragma unroll
            for (int i = 0; i < 4; ++i)
                v[i] = *(const uint2*)(xb_in + (size_t)(e[i] >> 15) * 32 + 2 * ql);
#pragma unroll
            for (int i = 0; i < 4; ++i) {
                float uu = (float)(e[i] & 0x7fffu) * inv15;
                float wa = (1.0f - uu) * m[i], wu = uu * m[i];
                float c0 = __uint_as_float(v[i].x << 16);
                float c1 = __uint_as_float(v[i].x & 0xffff0000u);
                float c2 = __uint_as_float(v[i].y << 16);
                float c3 = __uint_as_float(v[i].y & 0xffff0000u);
                a0 += wa * c0; a1 += wa * c1; a2 += wa * c2; a3 += wa * c3;
                b0 += wu * c0; b1 += wu * c1; b2 += wu * c2; b3 += wu * c3;
            }
        }
        float s = 1.0f / fmaxf((float)(end - start), 1.0f);
        int row = wave * 16 + q * 4 + t;
        *(uint2*)&gl[row][2 * ql] = make_uint2(bfpack(a0 * s, a1 * s), bfpack(a2 * s, a3 * s));
        *(uint2*)&gl[row][32 + 2 * ql] = make_uint2(bfpack(b0 * s, b1 * s), bfpack(b2 * s, b3 * s));
    }
    // no __syncthreads: each wave's epilogue reads only rows its own lanes wrote

    // --- MFMA epilogue (m92-verified layout) ---
    int quad = lane >> 4;
    int m16 = lane & 15;
    int arow = nodew + m16;
    const short* gp = (const short*)&gl[wave * 16 + m16][0];
    const unsigned* xp = xb_in + (size_t)arow * 32;
    bf16x8 zf = {0, 0, 0, 0, 0, 0, 0, 0};
    bf16x8 aG0[2], aG1[2], aX[2];
#pragma unroll
    for (int kf = 0; kf < 2; ++kf) {
        aG0[kf] = *(const bf16x8*)(gp + kf * 32 + quad * 8);
        aG1[kf] = *(const bf16x8*)(gp + 64 + kf * 32 + quad * 8);
        aX[kf] = (arow < n_nodes) ? *(const bf16x8*)(xp + kf * 16 + quad * 4) : zf;
    }
#pragma unroll
    for (int nt = 0; nt < 4; ++nt) {
        f32x4 acc = {0.f, 0.f, 0.f, 0.f};
#pragma unroll
        for (int kf = 0; kf < 2; ++kf) {
            int col = nt * 16 + m16;
            bf16x8 bw0 = *(const bf16x8*)(wb + (col << 6) + kf * 32 + quad * 8);
            bf16x8 bw1 = *(const bf16x8*)(wb + ((64 + col) << 6) + kf * 32 + quad * 8);
            bf16x8 bwR = *(const bf16x8*)(wb + ((128 + col) << 6) + kf * 32 + quad * 8);
            acc = __builtin_amdgcn_mfma_f32_16x16x32_bf16(aG0[kf], bw0, acc, 0, 0, 0);
            acc = __builtin_amdgcn_mfma_f32_16x16x32_bf16(aG1[kf], bw1, acc, 0, 0, 0);
            acc = __builtin_amdgcn_mfma_f32_16x16x32_bf16(aX[kf], bwR, acc, 0, 0, 0);
        }
        float bcol = bias[nt * 16 + m16];
#pragma unroll
        for (int r = 0; r < 4; ++r) {
            int node = nodew + quad * 4 + r;
            if (node < n_nodes) {
                size_t off = (size_t)node * CDIM + nt * 16 + m16;
                float o = acc[r] + bcol;
                if (out) out[off] = o;
                if (xb_out) xb_out[off] = (unsigned short)bf16r(o);
            }
        }
    }
}

extern "C" void kernel_launch(void* const* d_in, const int* in_sizes, int n_in,
                              void* d_out, int out_size, void* d_ws, size_t ws_size,
                              hipStream_t stream) {
    const float* x = (const float*)d_in[0];
    const int* edge_index = (const int*)d_in[1];
    const float* edge_attr = (const float*)d_in[2];
    const float* w1 = (const float*)d_in[3];
    const float* root1 = (const float*)d_in[4];
    const float* b1 = (const float*)d_in[5];
    const float* w2 = (const float*)d_in[6];
    const float* root2 = (const float*)d_in[7];
    const float* b2 = (const float*)d_in[8];

    int n_nodes = in_sizes[0] / CDIM;
    int n_edges = in_sizes[2];
    const int* src = edge_index;
    const int* dst = edge_index + n_edges;

    size_t F = (size_t)n_nodes * CDIM;
    unsigned* xbA = (unsigned*)d_ws;              // F/2 u32: bf16(x)
    unsigned* xbB = xbA + F / 2;                  // F/2 u32: bf16(layer-1 out)
    unsigned* em32 = xbB + F / 2;                 // E u32 (src<<15 | u15)
    int* row_start = (int*)(em32 + n_edges);      // n+1
    int n_buckets = (n_nodes + BKN - 1) >> NPB_SHIFT;   // 196
    int* ebase = row_start + n_nodes + 1;         // n_buckets
    int* bkt_cursor = ebase + n_buckets;          // n_buckets
    uintptr_t p = (uintptr_t)(bkt_cursor + n_buckets);
    p = (p + 15) & ~(uintptr_t)15;
    short* wtg = (short*)p;                       // [2][3][64][64] bf16
    p += (size_t)2 * 3 * 4096 * sizeof(short);
    p = (p + 15) & ~(uintptr_t)15;
    unsigned long long* rec = (unsigned long long*)p;  // n_buckets*BPAD u64
    float* out = (float*)d_out;

    int gB = (n_nodes + 63) / 64;                 // 64 nodes per fused block
    int gP = (n_edges + PART_CH - 1) / PART_CH;   // 782

    // ---- CSR build + packs/preps ----
    k_pack<<<2048, 256, 0, stream>>>(x, xbA, F / 2);
    k_prep<<<3, 256, 0, stream>>>(bkt_cursor, n_buckets, w1, root1, w2, root2, wtg);
    k_part<<<gP, 256, 0, stream>>>(src, dst, edge_attr, bkt_cursor, rec, n_edges, n_buckets);
    k_bscan<<<1, 256, 0, stream>>>(bkt_cursor, ebase, row_start, n_buckets, n_nodes);
    k_scat2<<<n_buckets, 1024, 0, stream>>>(rec, bkt_cursor, ebase, row_start, em32, n_nodes);

    // ---- layer 1 (bf16 out only) ----
    k_fused<<<gB, 256, 0, stream>>>(xbA, em32, row_start, wtg, b1,
                                    nullptr, (unsigned short*)xbB, n_nodes);
    // ---- layer 2 (fp32 out) ----
    k_fused<<<gB, 256, 0, stream>>>(xbB, em32, row_start, wtg + 3 * 4096, b2,
                                    out, nullptr, n_nodes);
}